// Round 4
// baseline (176.978 us; speedup 1.0000x reference)
//
#include <hip/hip_runtime.h>
#include <hip/hip_fp16.h>
#include <math.h>

// Problem constants: B=4, M=4096, D=64, W=128
constexpr int B = 4;
constexpr int M = 4096;
constexpr int D = 64;
constexpr int W = 128;
constexpr int NELEM = B * M * D;   // per-tensor elements

constexpr int T  = 128;            // k-rows per LDS tile
constexpr int NT = M / T;          // 32 tiles
constexpr int RB = 64;             // m-rows per block

typedef _Float16 h2_t __attribute__((ext_vector_type(2)));
typedef int      i4_t __attribute__((ext_vector_type(4)));

typedef __attribute__((address_space(1))) const void* gptr_t;
typedef __attribute__((address_space(3))) void*       sptr_t;

// ---- pass 1: fp32 -> fp16 of k AND v in a single launch ----
__global__ __launch_bounds__(256) void cvt_f32_f16_2(
    const float4* __restrict__ k, const float4* __restrict__ v,
    __half2* __restrict__ kh, __half2* __restrict__ vh, int n4) {
    int i = blockIdx.x * 256 + threadIdx.x;
    const float4* src;
    __half2* dst;
    if (i < n4) { src = k; dst = kh; }
    else        { src = v; dst = vh; i -= n4; if (i >= n4) return; }
    float4 f = src[i];
    dst[2 * i]     = __floats2half2_rn(f.x, f.y);
    dst[2 * i + 1] = __floats2half2_rn(f.z, f.w);
}

// ---- pass 2: bucket each row's 128 indices by tile (idx>>7). One wave per
// m-row; ballot/popcount compaction. Order within a bucket is arbitrary —
// softmax+PV is permutation-invariant in w. idx is shared across batches.
__global__ __launch_bounds__(256) void bucket_idx(
    const int* __restrict__ idx, unsigned short* __restrict__ idx2,
    int* __restrict__ off) {
    const int m    = blockIdx.x * 4 + (threadIdx.x >> 6);
    const int lane = threadIdx.x & 63;
    const int* row = idx + (size_t)m * W;
    const int j0 = row[lane], j1 = row[lane + 64];
    const int b0 = j0 >> 7,   b1 = j1 >> 7;
    unsigned short* o2 = idx2 + (size_t)m * W;
    int* op = off + (size_t)m * (NT + 1);
    const unsigned long long lt = (1ULL << lane) - 1ULL;
    int base = 0;
    for (int t = 0; t < NT; ++t) {
        unsigned long long q0 = __ballot(b0 == t);
        unsigned long long q1 = __ballot(b1 == t);
        if (lane == 0) op[t] = base;
        const int c0 = __popcll(q0);
        if (b0 == t) o2[base + __popcll(q0 & lt)] = (unsigned short)j0;
        if (b1 == t) o2[base + c0 + __popcll(q1 & lt)] = (unsigned short)j1;
        base += c0 + __popcll(q1);
    }
    if (lane == 0) op[NT] = base;   // == 128
}

// ---- main kernel: tiled dense-stream + LDS gather.
// The R0-R3 gather kernels were pinned at ~45us: 512 MB of random 128-B
// gathers saturate the per-CU L1 miss path (~32 MSHRs x 128 B / ~200cy L2
// ~= 45 GB/s/CU); NT-policy and MLP restructures both measured ZERO delta.
// Here K/V tiles are STREAMED (coalesced global_load_lds, no misses to
// track per-row) and the random access happens in LDS. Block = 64 m-rows
// x one batch; 8 waves x 8-lane groups (group = one m-row, lane c owns
// dims [c*8,c*8+8)). Online softmax with defer-max THR=8. Double-buffered
// staging, counted vmcnt(4) + raw barriers (never drain the pipe).
// 16-B chunks XOR-swizzled by row&7 (rows are 128 B = exactly 32 banks,
// so unswizzled chunk c always lands on banks 4c..4c+3).
__global__ __launch_bounds__(512, 2) void sparse_attn_tiled(
    const float* __restrict__ q,
    const __half* __restrict__ kh,
    const __half* __restrict__ vh,
    const unsigned short* __restrict__ idx2,
    const int* __restrict__ off,
    float* __restrict__ out)
{
    const int blk  = blockIdx.x;
    const int b    = blk & 3;              // XCD pinning: XCD x serves b=x&3
    const int mc   = blk >> 2;             // 0..63
    const int tid  = threadIdx.x;
    const int wave = tid >> 6;
    const int lane = tid & 63;
    const int g    = lane >> 3;            // group (row) within wave
    const int c    = lane & 7;             // dim-chunk: dims [c*8, c*8+8)
    const int mi   = wave * 8 + g;         // 0..63 local row
    const int m    = mc * RB + mi;

    __shared__ i4_t ktile[2][T][8];                    // 32 KB
    __shared__ i4_t vtile[2][T][8];                    // 32 KB
    __shared__ __align__(16) unsigned short idx2_s[RB * W];   // 16 KB
    __shared__ unsigned short off_s[RB][NT + 1];       // 4.2 KB

    // ---- prologue: idx2 + off into LDS ----
    {
        const i4_t* src = (const i4_t*)(idx2 + (size_t)mc * RB * W);
        i4_t* dst = (i4_t*)idx2_s;
        dst[tid]       = src[tid];
        dst[tid + 512] = src[tid + 512];
        const int* os = off + (size_t)mc * RB * (NT + 1);
        unsigned short* od = &off_s[0][0];
        for (int i = tid; i < RB * (NT + 1); i += 512)
            od[i] = (unsigned short)os[i];
    }

    // q fragment for this lane: dims [c*8, c*8+8) as 4x half2 for fdot2
    const float* qrow = q + ((size_t)b * M + m) * D + c * 8;
    const float4 qa = ((const float4*)qrow)[0];
    const float4 qb = ((const float4*)qrow)[1];
    h2_t qh[4];
    qh[0] = (h2_t){(_Float16)qa.x, (_Float16)qa.y};
    qh[1] = (h2_t){(_Float16)qa.z, (_Float16)qa.w};
    qh[2] = (h2_t){(_Float16)qb.x, (_Float16)qb.y};
    qh[3] = (h2_t){(_Float16)qb.z, (_Float16)qb.w};

    __syncthreads();   // idx LDS ready; drains all prologue loads (vmcnt=0)

    const char* kb = (const char*)(kh + (size_t)b * M * D);
    const char* vb = (const char*)(vh + (size_t)b * M * D);

    const int lr8 = lane >> 3;                 // staging row-sub 0..7
    const int swz = ((lane & 7) ^ lr8) * 16;   // chunk swizzle byte offset

    // Each wave stages rows [wave*16, wave*16+16) of K and V: 4 gl_lds/tile.
    // LDS dest is wave-uniform base + lane*16 (linear); swizzle achieved by
    // pre-swizzling the per-lane GLOBAL source (m173 pattern).
    auto stage = [&](int p, int t) {
        const int r0 = wave * 16;
        const size_t g0 = (size_t)t * T + r0;
        __builtin_amdgcn_global_load_lds(
            (gptr_t)(kb + (g0 + lr8) * 128 + swz),
            (sptr_t)&ktile[p][r0][0], 16, 0, 0);
        __builtin_amdgcn_global_load_lds(
            (gptr_t)(kb + (g0 + 8 + lr8) * 128 + swz),
            (sptr_t)&ktile[p][r0 + 8][0], 16, 0, 0);
        __builtin_amdgcn_global_load_lds(
            (gptr_t)(vb + (g0 + lr8) * 128 + swz),
            (sptr_t)&vtile[p][r0][0], 16, 0, 0);
        __builtin_amdgcn_global_load_lds(
            (gptr_t)(vb + (g0 + 8 + lr8) * 128 + swz),
            (sptr_t)&vtile[p][r0 + 8][0], 16, 0, 0);
    };

    float acc[8] = {0, 0, 0, 0, 0, 0, 0, 0};
    float mrun = -1e30f;
    float l = 0.f;

    stage(0, 0);
    stage(1, 1);     // 8 gl_lds outstanding per wave

    for (int t = 0; t < NT; ++t) {
        const int p = t & 1;
        // current buffer's 4 loads done; next tile's 4 stay in flight
        if (t < NT - 1) asm volatile("s_waitcnt vmcnt(4)" ::: "memory");
        else            asm volatile("s_waitcnt vmcnt(0)" ::: "memory");
        __builtin_amdgcn_s_barrier();
        asm volatile("" ::: "memory");   // no LDS reads hoist above barrier

        const int base = off_s[mi][t];
        const int cnt  = off_s[mi][t + 1] - base;
        const unsigned short* ip = &idx2_s[mi * W + base];
        for (int e = 0; e < cnt; ++e) {
            const int jj = ip[e];
            const int lr = jj & (T - 1);
            union { i4_t v; h2_t h[4]; } uk, uv;
            uk.v = ktile[p][lr][c ^ (lr & 7)];
            float part = 0.f;
            part = __builtin_amdgcn_fdot2(uk.h[0], qh[0], part, false);
            part = __builtin_amdgcn_fdot2(uk.h[1], qh[1], part, false);
            part = __builtin_amdgcn_fdot2(uk.h[2], qh[2], part, false);
            part = __builtin_amdgcn_fdot2(uk.h[3], qh[3], part, false);
            part += __shfl_xor(part, 1);
            part += __shfl_xor(part, 2);
            part += __shfl_xor(part, 4);   // all 8 group lanes hold logit
            float d = part - mrun;
            if (d > 8.0f) {                // defer-max: rare rescale
                const float s = __expf(-d);
                l *= s;
                #pragma unroll
                for (int i = 0; i < 8; ++i) acc[i] *= s;
                mrun = part;
                d = 0.f;
            }
            const float pw = __expf(d);    // bounded by e^8
            l += pw;
            uv.v = vtile[p][lr][c ^ (lr & 7)];
            #pragma unroll
            for (int k2 = 0; k2 < 4; ++k2) {
                acc[2 * k2]     += pw * (float)uv.h[k2][0];
                acc[2 * k2 + 1] += pw * (float)uv.h[k2][1];
            }
        }

        asm volatile("s_waitcnt lgkmcnt(0)" ::: "memory");
        __builtin_amdgcn_s_barrier();      // all waves done reading buf p
        asm volatile("" ::: "memory");
        if (t + 2 < NT) stage(p, t + 2);   // safe to overwrite p now
    }

    const float inv = 1.0f / l;
    float* orow = out + ((size_t)b * M + m) * D + c * 8;
    ((float4*)orow)[0] = make_float4(acc[0] * inv, acc[1] * inv,
                                     acc[2] * inv, acc[3] * inv);
    ((float4*)orow)[1] = make_float4(acc[4] * inv, acc[5] * inv,
                                     acc[6] * inv, acc[7] * inv);
}

// ---- fallback fp32 kernel (R1 structure) if workspace too small ----
__global__ __launch_bounds__(128) void sparse_attn_f32(
    const float* __restrict__ q,
    const float* __restrict__ k,
    const float* __restrict__ v,
    const int*   __restrict__ idx,
    float*       __restrict__ out)
{
    const int blk = blockIdx.x;
    const int b = blk & 3;
    const int m = blk >> 2;
    const int t = threadIdx.x;
    const int lane = t & 63;
    const int wave = t >> 6;
    const int ci = lane & 15;
    const int r  = lane >> 4;

    __shared__ int   idx_s[W];
    __shared__ float sc_s[W];
    __shared__ float red_s[4];
    __shared__ float4 opart_s[16];

    idx_s[t] = idx[m * W + t];
    const float4 qf = ((const float4*)(q + ((size_t)b * M + m) * D))[ci];
    __syncthreads();

    const float* kb = k + (size_t)b * M * D;
    const int wbase = wave * 64;

    #pragma unroll
    for (int j = 0; j < 16; ++j) {
        const int w = wbase + j * 4 + r;
        const float4 kv = ((const float4*)(kb + (size_t)idx_s[w] * D))[ci];
        float part = kv.x * qf.x + kv.y * qf.y + kv.z * qf.z + kv.w * qf.w;
        part += __shfl_xor(part, 1);
        part += __shfl_xor(part, 2);
        part += __shfl_xor(part, 4);
        part += __shfl_xor(part, 8);
        if (ci == 0) sc_s[w] = part;
    }
    __syncthreads();

    float logit = sc_s[t];
    float mx = logit;
    #pragma unroll
    for (int o = 1; o < 64; o <<= 1) mx = fmaxf(mx, __shfl_xor(mx, o));
    if (lane == 0) red_s[wave] = mx;
    __syncthreads();
    mx = fmaxf(red_s[0], red_s[1]);
    float e = __expf(logit - mx);
    float sm = e;
    #pragma unroll
    for (int o = 1; o < 64; o <<= 1) sm += __shfl_xor(sm, o);
    if (lane == 0) red_s[2 + wave] = sm;
    __syncthreads();
    const float inv_denom = 1.0f / (red_s[2] + red_s[3]);
    sc_s[t] = e * inv_denom;
    __syncthreads();

    const float* vb = v + (size_t)b * M * D;
    float4 acc = {0.f, 0.f, 0.f, 0.f};
    #pragma unroll
    for (int j = 0; j < 16; ++j) {
        const int w = wbase + j * 4 + r;
        const float p = sc_s[w];
        const float4 vv = ((const float4*)(vb + (size_t)idx_s[w] * D))[ci];
        acc.x += p * vv.x; acc.y += p * vv.y;
        acc.z += p * vv.z; acc.w += p * vv.w;
    }
    acc.x += __shfl_xor(acc.x, 16); acc.y += __shfl_xor(acc.y, 16);
    acc.z += __shfl_xor(acc.z, 16); acc.w += __shfl_xor(acc.w, 16);
    acc.x += __shfl_xor(acc.x, 32); acc.y += __shfl_xor(acc.y, 32);
    acc.z += __shfl_xor(acc.z, 32); acc.w += __shfl_xor(acc.w, 32);

    if (wave == 0 && r == 0) opart_s[ci] = acc;
    __syncthreads();
    if (wave == 1 && r == 0) {
        const float4 o0 = opart_s[ci];
        float4 res;
        res.x = o0.x + acc.x; res.y = o0.y + acc.y;
        res.z = o0.z + acc.z; res.w = o0.w + acc.w;
        ((float4*)(out + ((size_t)b * M + m) * D))[ci] = res;
    }
}

extern "C" void kernel_launch(void* const* d_in, const int* in_sizes, int n_in,
                              void* d_out, int out_size, void* d_ws, size_t ws_size,
                              hipStream_t stream) {
    const float* q = (const float*)d_in[0];
    const float* k = (const float*)d_in[1];
    const float* v = (const float*)d_in[2];
    const int* idx = (const int*)d_in[3];
    float* out = (float*)d_out;

    // workspace layout: kh (2 MB) | vh (2 MB) | idx2 u16 (1 MB) | off (~528 KB)
    const size_t sz_kv   = (size_t)NELEM * sizeof(__half);            // 2 MiB each
    const size_t sz_idx2 = (size_t)M * W * sizeof(unsigned short);    // 1 MiB
    const size_t sz_off  = (size_t)M * (NT + 1) * sizeof(int);
    const size_t need = 2 * sz_kv + sz_idx2 + sz_off;
    if (ws_size >= need) {
        __half* khp = (__half*)d_ws;
        __half* vhp = khp + NELEM;
        unsigned short* idx2 = (unsigned short*)((char*)d_ws + 2 * sz_kv);
        int* off = (int*)((char*)d_ws + 2 * sz_kv + sz_idx2);

        const int n4 = NELEM / 4;
        const int cblk = (2 * n4 + 255) / 256;
        cvt_f32_f16_2<<<cblk, 256, 0, stream>>>((const float4*)k, (const float4*)v,
                                                (__half2*)khp, (__half2*)vhp, n4);
        bucket_idx<<<M / 4, 256, 0, stream>>>(idx, idx2, off);
        sparse_attn_tiled<<<B * M / RB, 512, 0, stream>>>(q, khp, vhp, idx2, off, out);
    } else {
        sparse_attn_f32<<<B * M, 128, 0, stream>>>(q, k, v, idx, out);
    }
}